// Round 7
// baseline (1039.304 us; speedup 1.0000x reference)
//
#include <hip/hip_runtime.h>
#include <hip/hip_bf16.h>

// R7 theory: R6's +1e8 conflicts = unswizzled inline fragment-linear x stores (8-way:
// fixed s -> banks {0,2} only) + P store at 208B stride (4-way, bank-step order 8).
// Fix 1: stage-tile XOR swizzle (^(ks<<5)^(khalf<<4)) on stores AND fragment reads;
//        W images pre-swizzled in ws (gload stays linear).
// Fix 2: P stride 216B (bank-step 22 mod 32, order 16 -> all 16 even banks, min-cycle);
//        P reads via 8B-aligned b64 pairs. Layout: PL 14,256; vT/Wc 28,512; aoT 42,096.
// Predicted: conflicts <=2e7, main ~690us, total ~850us, VALU ~44%, MFMA ~26%.

constexpr int T  = 6;
constexpr int S  = 66;    // 3*J
constexpr int IN = 256;
constexpr int H  = 8;
constexpr int D  = 32;
constexpr int J  = 22;
constexpr float NEG = -9e15f;
constexpr float INV_SQRT_D = 0.17677669529663688110f; // 1/sqrt(32)

// ---------------- LDS map (bytes), SMEM 49,152 -> 3 blocks/CU ------------------------
// stage (per 64-K chunk): x m01 frag tiles [8 hi|8 lo]x1KB @0..16,384;
//   x m2 tiles (rows 64..95): hi @16,384, lo @20,480 (zero-init once);
//   W frag tiles [12 hi|12 lo]x1KB @24,576..49,152.  All tiles XOR-swizzled:
//   within-tile byte ^= (ks<<5) ^ (khalf<<4).
// attn persistent: qh/ql [66][36] @0/4,752; kh/kl @9,504/14,256 (end 19,008);
//   vTh/vTl bf16[32][104] @28,512/35,168 (208B rows, end 41,824);
//   inv f32[66] @41,824..42,088; aoT bf16[32][104] @42,096..48,752.
// overlays: Ph/Pl bf16 216B-stride rows @0/14,256 (end 28,512, after q/k dead);
//   Wch/Wcl @28,512/35,168 (vT dead).
#define XM2H_OFF 16384
#define XM2L_OFF 20480
#define W_OFF    24576
#define W_LO     12288
#define QH_OFF   0
#define QL_OFF   4752
#define KH_OFF   9504
#define KL_OFF   14256
#define VTH_OFF  28512
#define VTL_OFF  35168
#define INV_OFF  41824
#define AOT_OFF  42096
#define PH_OFF   0
#define PL_OFF   14256
#define P_STRIDE 216
#define WCH_OFF  28512
#define WCL_OFF  35168
#define SMEM_BYTES 49152

// ws: 32 W images (h*4+chunk) of [12 hi|12 lo]x1KB = 24,576 -> 786,432 (pre-swizzled);
// Wc image [hi 32x208B | lo 32x208B] = 13,312 -> 799,744.
#define WSW_STRIDE 24576
#define WSWC_OFF   786432
#define WS_W       799744ull

typedef float f32x4   __attribute__((ext_vector_type(4)));
typedef float f32x16  __attribute__((ext_vector_type(16)));
typedef short bf16x8  __attribute__((ext_vector_type(8)));
typedef short s4v     __attribute__((ext_vector_type(4)));

__device__ __forceinline__ unsigned cvtpk(float a, float b) {
    unsigned r;
    asm("v_cvt_pk_bf16_f32 %0, %1, %2" : "=v"(r) : "v"(a), "v"(b));
    return r;   // low16 = bf16(a), high16 = bf16(b), RNE
}
__device__ __forceinline__ float bfh2f(unsigned short h) {
    return __uint_as_float(((unsigned)h) << 16);
}
__device__ __forceinline__ void split2(float a, float b, unsigned& hi, unsigned& lo) {
    unsigned h = cvtpk(a, b);
    float ra = a - __uint_as_float(h << 16);
    float rb = b - __uint_as_float(h & 0xffff0000u);
    lo = cvtpk(ra, rb);
    hi = h;
}
__device__ __forceinline__ bf16x8 ld_bf16x8_a8(const short* p) {
    s4v a = *(const s4v*)p;
    s4v b = *(const s4v*)(p + 4);
    return __builtin_shufflevector(a, b, 0, 1, 2, 3, 4, 5, 6, 7);
}
__device__ __forceinline__ void gload16(const void* g, void* l) {
    __builtin_amdgcn_global_load_lds(
        (const __attribute__((address_space(1))) unsigned*)g,
        (__attribute__((address_space(3))) unsigned*)l, 16, 0, 0);
}

// ---------------- pre-kernel: W(h,chunk) fragment images (swizzled) + Wc image -------
__global__ __launch_bounds__(256)
void presplit_kernel(const float* __restrict__ Wq, const float* __restrict__ Wk,
                     const float* __restrict__ Wv, const float* __restrict__ Wc,
                     unsigned char* __restrict__ ws)
{
    int gid = blockIdx.x * 256 + threadIdx.x;
    if (gid < 49152) {                     // 32 images x 96 rows x 16 col-groups
        int img = gid / 1536, u = gid - img * 1536;
        int row = u >> 4, c = u & 15, k0 = c << 2;
        int mat = row >> 5, dd = row & 31;
        int chunk = img & 3, hh = img >> 2;
        const float* Wm = (mat == 0) ? Wq : (mat == 1) ? Wk : Wv;
        float4 v = *(const float4*)(Wm + (size_t)(hh * 32 + dd) * IN + chunk * 64 + c * 4);
        uint2 hi, lo;
        split2(v.x, v.y, hi.x, lo.x);
        split2(v.z, v.w, hi.y, lo.y);
        int ks = k0 >> 4, khalf = (k0 >> 3) & 1;
        int tile  = (mat << 2) + ks;
        int lanei = dd + (khalf << 5);
        int off   = (((lanei << 4) + ((k0 & 7) << 1)) ^ (ks << 5)) ^ (khalf << 4);
        int byte  = (tile << 10) + off;
        unsigned char* base = ws + (size_t)img * WSW_STRIDE;
        *(uint2*)(base + byte)        = hi;
        *(uint2*)(base + W_LO + byte) = lo;
    } else if (gid < 49152 + 1664) {       // Wc image: 32 rows x 52 dword cols (zero-padded)
        int g2  = gid - 49152;
        int row = g2 / 52, cu = g2 - row * 52;
        int c0  = 2 * cu;
        float a = (row < 22 && c0     < 66) ? Wc[row * 66 + c0]     : 0.f;
        float b = (row < 22 && c0 + 1 < 66) ? Wc[row * 66 + c0 + 1] : 0.f;
        unsigned hi, lo;
        split2(a, b, hi, lo);
        *(unsigned*)(ws + WSWC_OFF + row * 208 + 4 * cu)        = hi;
        *(unsigned*)(ws + WSWC_OFF + 6656 + row * 208 + 4 * cu) = lo;
    }
}

// MODE: 0 = all inline, 1 = W/Wc presplit (default)
template<int MODE>
__global__ __launch_bounds__(256, 3)
void mha_fused_kernel(const float* __restrict__ x,
                      const float* __restrict__ Wq, const float* __restrict__ bq,
                      const float* __restrict__ Wk, const float* __restrict__ bk,
                      const float* __restrict__ Wv, const float* __restrict__ bv,
                      const float* __restrict__ Wc, const float* __restrict__ bc,
                      const unsigned char* __restrict__ ws,
                      float* __restrict__ out)
{
    __shared__ __align__(16) unsigned char smem[SMEM_BYTES];

    const int tid = threadIdx.x;
    // bt-grouping XCD swizzle: 8 heads of one bt land on one XCD, adjacent in time.
    const int i0  = blockIdx.x;
    const int h   = (i0 >> 3) & 7;
    const int bt  = (i0 & 7) | ((i0 >> 6) << 3);   // bijective over [0,3072)

    const int wid  = tid >> 6;           // wave 0..3
    const int lane = tid & 63;
    const int l15  = lane & 15;
    const int quad = lane >> 4;
    // fragment-read lane offset incl. khalf XOR: (lane<<4) ^ ((lane>>5)<<4)
    const int laneSwz = (lane << 4) ^ ((lane & 32) >> 1);

    // zero x-m2 tiles once (rows 66..95 stay zero; rows 64/65 rewritten per chunk)
    for (int u = tid; u < 512; u += 256)
        *(uint4*)(smem + XM2H_OFF + u * 16) = (uint4){0u, 0u, 0u, 0u};

    // ---------------- Phase 1: q,k,v projections via split-bf16 32x32x16 MFMA --------
    const f32x16 zacc = {0.f,0.f,0.f,0.f,0.f,0.f,0.f,0.f,0.f,0.f,0.f,0.f,0.f,0.f,0.f,0.f};
    f32x16 accs[3] = {zacc, zacc, zacc};

    const float* xg0 = x + (size_t)bt * S * IN;
    for (int chunk = 0; chunk < 4; ++chunk) {    // K = 4 x 64
        __syncthreads();
        const float* xg = xg0 + chunk * 64;
        if constexpr (MODE == 1) {
            const unsigned char* wimg = ws + (size_t)((h << 2) | chunk) * WSW_STRIDE;
            for (int i = wid; i < 24; i += 4)
                gload16(wimg + (i << 10) + (lane << 4), smem + W_OFF + (i << 10));
        } else {
            for (int u = tid; u < 1536; u += 256) {   // W inline -> swizzled fragments
                int row = u >> 4, c = u & 15, k0 = c << 2;
                int mat = row >> 5, dd2 = row & 31;
                const float* Wm = (mat == 0) ? Wq : (mat == 1) ? Wk : Wv;
                float4 v = *(const float4*)(Wm + (size_t)(h * 32 + dd2) * IN + chunk * 64 + c * 4);
                uint2 hi, lo;
                split2(v.x, v.y, hi.x, lo.x);
                split2(v.z, v.w, hi.y, lo.y);
                int ks = k0 >> 4, khalf = (k0 >> 3) & 1;
                int tile  = (mat << 2) + ks;
                int lanei = dd2 + (khalf << 5);
                int off   = (((lanei << 4) + ((k0 & 7) << 1)) ^ (ks << 5)) ^ (khalf << 4);
                int byte  = (tile << 10) + off;
                *(uint2*)(smem + W_OFF + byte)        = hi;
                *(uint2*)(smem + W_OFF + W_LO + byte) = lo;
            }
        }
        // x inline -> swizzled fragments (rows 0..65; 66..95 remain zero from init)
        for (int u = tid; u < 1536; u += 256) {
            int s = u >> 4, c = u & 15, k0 = c << 2;
            if (s >= 66) continue;
            float4 v = *(const float4*)(xg + (size_t)s * IN + c * 4);
            uint2 hi, lo;
            split2(v.x, v.y, hi.x, lo.x);
            split2(v.z, v.w, hi.y, lo.y);
            int ks = k0 >> 4, khalf = (k0 >> 1) & 1 ? 0 : 0;   // placeholder (recomputed)
            khalf = (k0 >> 3) & 1;
            int b = (k0 & 7) << 1;
            int off = (((((s & 31) + (khalf << 5)) << 4) + b) ^ (ks << 5)) ^ (khalf << 4);
            int toff = (ks << 10) + off;
            if (s < 64) {
                int base = (s >> 5) * 4096 + toff;
                *(uint2*)(smem + base)        = hi;
                *(uint2*)(smem + base + 8192) = lo;
            } else {
                *(uint2*)(smem + XM2H_OFF + toff) = hi;
                *(uint2*)(smem + XM2L_OFF + toff) = lo;
            }
        }
        __syncthreads();

        #pragma unroll
        for (int t = 0; t < 3; ++t) {
            int p = wid + 4 * t;                 // p = mtile*3 + mat, over [0,9)
            if (p >= 9) break;                   // wave-uniform
            int mtile = p / 3, mat = p - mtile * 3;
            const unsigned char *xaH0, *xaL0;
            if (mtile < 2) { xaH0 = smem + mtile * 4096; xaL0 = xaH0 + 8192; }
            else           { xaH0 = smem + XM2H_OFF;     xaL0 = xaH0 + 4096; }
            const unsigned char* wbH0 = smem + W_OFF + mat * 4096;
            #pragma unroll
            for (int ks = 0; ks < 4; ++ks) {
                int off = (ks << 10) + (laneSwz ^ (ks << 5));
                bf16x8 ah = *(const bf16x8*)(xaH0 + off);
                bf16x8 al = *(const bf16x8*)(xaL0 + off);
                bf16x8 bh = *(const bf16x8*)(wbH0 + off);
                bf16x8 bl = *(const bf16x8*)(wbH0 + off + W_LO);
                accs[t] = __builtin_amdgcn_mfma_f32_32x32x16_bf16(ah, bh, accs[t], 0, 0, 0);
                accs[t] = __builtin_amdgcn_mfma_f32_32x32x16_bf16(ah, bl, accs[t], 0, 0, 0);
                accs[t] = __builtin_amdgcn_mfma_f32_32x32x16_bf16(al, bh, accs[t], 0, 0, 0);
            }
        }
    }
    __syncthreads();   // stage dead; epilogue overwrites it

    // -------- Epilogue: q/k -> hi/lo [s][d]; v -> relu, hi/lo transposed [d][s] ------
    // 32x32 C/D layout: col = lane&31, row = (reg&3) + 8*(reg>>2) + 4*(lane>>5).
    {
        short* qh = (short*)(smem + QH_OFF); short* ql = (short*)(smem + QL_OFF);
        short* kh = (short*)(smem + KH_OFF); short* kl = (short*)(smem + KL_OFF);
        const int dd = lane & 31;
        const int half = lane >> 5;
        #pragma unroll
        for (int t = 0; t < 3; ++t) {
            int p = wid + 4 * t;
            if (p >= 9) break;
            int mtile = p / 3, mat = p - mtile * 3;
            const float* bias_p = (mat == 0) ? bq : (mat == 1) ? bk : bv;
            float bias = bias_p[h * 32 + dd];
            if (mat < 2) {
                short* bh_ = (mat == 0) ? qh : kh;
                short* bl_ = (mat == 0) ? ql : kl;
                #pragma unroll
                for (int g = 0; g < 4; ++g) {
                    int sb2 = mtile * 32 + half * 4 + 8 * g;
                    uint2 hi, lo;
                    split2(accs[t][4*g+0] + bias, accs[t][4*g+1] + bias, hi.x, lo.x);
                    split2(accs[t][4*g+2] + bias, accs[t][4*g+3] + bias, hi.y, lo.y);
                    unsigned hs[4] = { hi.x & 0xffffu, hi.x >> 16, hi.y & 0xffffu, hi.y >> 16 };
                    unsigned ls[4] = { lo.x & 0xffffu, lo.x >> 16, lo.y & 0xffffu, lo.y >> 16 };
                    #pragma unroll
                    for (int r = 0; r < 4; ++r) {
                        int s = sb2 + r;
                        if (s < 66) {
                            bh_[s * 36 + dd] = (short)hs[r];
                            bl_[s * 36 + dd] = (short)ls[r];
                        }
                    }
                }
            } else {
                #pragma unroll
                for (int g = 0; g < 4; ++g) {
                    int sb2 = mtile * 32 + half * 4 + 8 * g;
                    float vv[4];
                    #pragma unroll
                    for (int r = 0; r < 4; ++r) {
                        int s = sb2 + r;
                        vv[r] = (s < 66) ? fmaxf(accs[t][4*g+r] + bias, 0.f) : 0.f;
                    }
                    uint2 ph, pl;
                    split2(vv[0], vv[1], ph.x, pl.x);
                    split2(vv[2], vv[3], ph.y, pl.y);
                    *(uint2*)(smem + VTH_OFF + dd * 208 + 2 * sb2) = ph;
                    *(uint2*)(smem + VTL_OFF + dd * 208 + 2 * sb2) = pl;
                }
            }
        }
    }
    __syncthreads();

    // ------- Phase 3+4 fused, SWAPPED: scores^T = K·Q^T ------------------------------
    // a = k rows (mk strip), b = q rows (mq strip). Output: row k = mk*16+quad*4+reg,
    // col q = mq*16+l15. Per lane: one q, 20 k-values -> k-reduce = in-lane + shfl 16,32.
    {
        const short* qh = (const short*)(smem + QH_OFF);
        const short* ql = (const short*)(smem + QL_OFF);
        const short* kh = (const short*)(smem + KH_OFF);
        const short* kl = (const short*)(smem + KL_OFF);

        auto qk_mfma = [&](int mq, f32x4* acc) {
            int boff = (mq * 16 + l15) * 36 + quad * 8;
            bf16x8 bh = ld_bf16x8_a8(qh + boff);
            bf16x8 bl = ld_bf16x8_a8(ql + boff);
            #pragma unroll
            for (int mk = 0; mk < 5; ++mk) {
                int aoff = (mk * 16 + l15) * 36 + quad * 8;
                bf16x8 ah = ld_bf16x8_a8(kh + aoff);
                bf16x8 al = ld_bf16x8_a8(kl + aoff);
                f32x4 a = (f32x4){0.f, 0.f, 0.f, 0.f};
                a = __builtin_amdgcn_mfma_f32_16x16x32_bf16(ah, bh, a, 0, 0, 0);
                a = __builtin_amdgcn_mfma_f32_16x16x32_bf16(ah, bl, a, 0, 0, 0);
                a = __builtin_amdgcn_mfma_f32_16x16x32_bf16(al, bh, a, 0, 0, 0);
                acc[mk] = a;
            }
        };

        f32x4 accA[5], accB[5];
        qk_mfma(wid, accA);
        if (wid == 3) qk_mfma(4, accB);
        __syncthreads();   // all q/k reads done -> P may overlay q/k

        unsigned char* Ph = smem + PH_OFF;
        unsigned char* Pl = smem + PL_OFF;
        float* inv = (float*)(smem + INV_OFF);

        auto sm_store = [&](int mq, f32x4* acc) {
            const int q = mq * 16 + l15;
            float v[5][4];
            #pragma unroll
            for (int mk = 0; mk < 5; ++mk) {
                #pragma unroll
                for (int reg = 0; reg < 4; ++reg) {
                    int k = mk * 16 + quad * 4 + reg;
                    bool invalid = (k >= 66);
                    bool masked = (q < J && k >= 2 * J) || (q >= 2 * J && k < J);
                    float s = acc[mk][reg] * INV_SQRT_D;
                    v[mk][reg] = invalid ? -INFINITY : (masked ? 0.f : s);
                }
            }
            float mm = -INFINITY;
            #pragma unroll
            for (int mk = 0; mk < 5; ++mk)
                #pragma unroll
                for (int reg = 0; reg < 4; ++reg) mm = fmaxf(mm, v[mk][reg]);
            mm = fmaxf(mm, __shfl_xor(mm, 16));
            mm = fmaxf(mm, __shfl_xor(mm, 32));
            const float thr = mm / 9.0f;
            float rm = -INFINITY;
            #pragma unroll
            for (int mk = 0; mk < 5; ++mk) {
                #pragma unroll
                for (int reg = 0; reg < 4; ++reg) {
                    float sv = v[mk][reg];
                    float pr = (fabsf(sv) <= thr) ? NEG : sv;   // -INF sentinels stay below
                    v[mk][reg] = pr;
                    rm = fmaxf(rm, pr);
                }
            }
            rm = fmaxf(rm, __shfl_xor(rm, 16));
            rm = fmaxf(rm, __shfl_xor(rm, 32));
            float e[5][4], lsum = 0.f;
            #pragma unroll
            for (int mk = 0; mk < 5; ++mk) {
                #pragma unroll
                for (int reg = 0; reg < 4; ++reg) {
                    float ev = __expf(v[mk][reg] - rm);   // -INF -> 0
                    e[mk][reg] = ev;
                    lsum += ev;
                }
            }
            lsum += __shfl_xor(lsum, 16);
            lsum += __shfl_xor(lsum, 32);
            if (q < 66) {
                #pragma unroll
                for (int mk = 0; mk < 5; ++mk) {
                    unsigned h0 = cvtpk(e[mk][0], e[mk][1]);
                    unsigned h1 = cvtpk(e[mk][2], e[mk][3]);
                    uint2 hi = {h0, h1}, lo;
                    lo.x = cvtpk(e[mk][0] - bfh2f((unsigned short)h0),
                                 e[mk][1] - bfh2f((unsigned short)(h0 >> 16)));
                    lo.y = cvtpk(e[mk][2] - bfh2f((unsigned short)h1),
                                 e[mk][3] - bfh2f((unsigned short)(h1 >> 16)));
                    int kb = (mk * 16 + quad * 4) * 2;
                    *(uint2*)(Ph + q * P_STRIDE + kb) = hi;
                    *(uint2*)(Pl + q * P_STRIDE + kb) = lo;
                }
                if (quad == 0) inv[q] = 1.0f / lsum;
            }
        };

        sm_store(wid, accA);
        if (wid == 3) sm_store(4, accB);

        // zero P cols 80..95 (bytes 160..191) rows 0..65, both components (uint2, 8B ok)
        for (int u = tid; u < 528; u += 256) {
            int comp = u >= 264 ? 1 : 0, rem = u - comp * 264;
            int row = rem >> 2, slot = rem & 3;
            *(uint2*)(smem + (comp ? PL_OFF : PH_OFF) + row * P_STRIDE + 160 + slot * 8)
                = (uint2){0u, 0u};
        }
    }
    __syncthreads();

    // ---------------- Phase 5: aoT = (P @ v)^T * inv, bf16-hi, via MFMA --------------
    {
        const short* Ph = (const short*)(smem + PH_OFF);
        const short* Pl = (const short*)(smem + PL_OFF);
        const short* vh = (const short*)(smem + VTH_OFF);
        const short* vl = (const short*)(smem + VTL_OFF);
        const float* inv = (const float*)(smem + INV_OFF);
        for (int t = 0; t < 3; ++t) {
            int tt = wid + 4 * t;
            if (tt >= 10) break;
            int mq = tt >> 1, nd = tt & 1;
            f32x4 acc = (f32x4){0.f, 0.f, 0.f, 0.f};
            #pragma unroll
            for (int ks = 0; ks < 3; ++ks) {
                // P rows at 216B stride (108 shorts): 8B-aligned -> b64-pair loads
                bf16x8 a   = ld_bf16x8_a8(Ph + (mq * 16 + l15) * 108 + ks * 32 + quad * 8);
                bf16x8 al8 = ld_bf16x8_a8(Pl + (mq * 16 + l15) * 108 + ks * 32 + quad * 8);
                bf16x8 b   = *(const bf16x8*)(vh + (nd * 16 + l15) * 104 + ks * 32 + quad * 8);
                bf16x8 bl8 = *(const bf16x8*)(vl + (nd * 16 + l15) * 104 + ks * 32 + quad * 8);
                acc = __builtin_amdgcn_mfma_f32_16x16x32_bf16(a, b, acc, 0, 0, 0);
                acc = __builtin_amdgcn_mfma_f32_16x16x32_bf16(al8, b, acc, 0, 0, 0);
                acc = __builtin_amdgcn_mfma_f32_16x16x32_bf16(a, bl8, acc, 0, 0, 0);
            }
            int dd = nd * 16 + l15, sbase = mq * 16 + quad * 4;
            float o[4];
            #pragma unroll
            for (int reg = 0; reg < 4; ++reg) {
                int qs = sbase + reg;
                o[reg] = (qs < 66) ? acc[reg] * inv[qs] : 0.f;
            }
            uint2 pk;
            pk.x = cvtpk(o[0], o[1]);
            pk.y = cvtpk(o[2], o[3]);
            *(uint2*)(smem + AOT_OFF + dd * 208 + 2 * sbase) = pk;
        }
        // zero aoT cols 80..103
        for (int u = tid; u < 384; u += 256) {
            int row = u / 12, kcol = 80 + 2 * (u % 12);
            *(unsigned*)(smem + AOT_OFF + row * 208 + 2 * kcol) = 0u;
        }
    }
    __syncthreads();

    // ---------------- Stage Wc hi/lo (overlays dead vT) ------------------------------
    if constexpr (MODE >= 1) {
        const unsigned char* wc = ws + WSWC_OFF;   // pre-built 13,312B image
        for (int i = wid; i < 13; i += 4)
            gload16(wc + (i << 10) + (lane << 4), smem + WCH_OFF + (i << 10));
    } else {
        for (int u = tid; u < 726; u += 256) {           // 22 rows x 33 float2
            int row = u / 33, cp = u - row * 33;
            float2 w = *(const float2*)(Wc + row * 66 + 2 * cp);
            unsigned hi, lo;
            split2(w.x, w.y, hi, lo);
            *(unsigned*)(smem + WCH_OFF + row * 208 + 4 * cp) = hi;
            *(unsigned*)(smem + WCL_OFF + row * 208 + 4 * cp) = lo;
        }
        for (int u = tid; u < 836; u += 256) {           // zero cols 66..103, rows 0..21
            int comp = u >= 418 ? 1 : 0, rem = comp ? u - 418 : u;
            int row = rem / 19, kcol = 66 + 2 * (rem % 19);
            *(unsigned*)(smem + (comp ? WCL_OFF : WCH_OFF) + row * 208 + 2 * kcol) = 0u;
        }
    }
    __syncthreads();

    // ---------------- Phase 6: out = Wc @ ao + bc via MFMA ---------------------------
    {
        const short* Wch = (const short*)(smem + WCH_OFF);
        const short* Wcl = (const short*)(smem + WCL_OFF);
        const short* aoT = (const short*)(smem + AOT_OFF);
        int mj = wid >> 1, nd = wid & 1;
        f32x4 acc = (f32x4){0.f, 0.f, 0.f, 0.f};
        #pragma unroll
        for (int ks = 0; ks < 3; ++ks) {
            bf16x8 a   = *(const bf16x8*)(Wch + (mj * 16 + l15) * 104 + ks * 32 + quad * 8);
            bf16x8 al8 = *(const bf16x8*)(Wcl + (mj * 16 + l15) * 104 + ks * 32 + quad * 8);
            bf16x8 b   = *(const bf16x8*)(aoT + (nd * 16 + l15) * 104 + ks * 32 + quad * 8);
            acc = __builtin_amdgcn_mfma_f32_16x16x32_bf16(a, b, acc, 0, 0, 0);
            acc = __builtin_amdgcn_mfma_f32_16x16x32_bf16(al8, b, acc, 0, 0, 0);
        }
        int dd = nd * 16 + l15;
        #pragma unroll
        for (int reg = 0; reg < 4; ++reg) {
            int j = mj * 16 + quad * 4 + reg;
            if (j < 22) {
                size_t o = (size_t)(bt * J + j) * (H * D) + h * 32 + dd;
                out[o] = acc[reg] + bc[j];
            }
        }
    }
}

extern "C" void kernel_launch(void* const* d_in, const int* in_sizes, int n_in,
                              void* d_out, int out_size, void* d_ws, size_t ws_size,
                              hipStream_t stream) {
    const float* x  = (const float*)d_in[0];
    const float* Wq = (const float*)d_in[1];
    const float* bq = (const float*)d_in[2];
    const float* Wk = (const float*)d_in[3];
    const float* bk = (const float*)d_in[4];
    const float* Wv = (const float*)d_in[5];
    const float* bv = (const float*)d_in[6];
    const float* Wc = (const float*)d_in[7];
    const float* bc = (const float*)d_in[8];
    float* out = (float*)d_out;

    const int B = 512;
    dim3 grid(B * T * H), block(256);
    if (d_ws != nullptr && ws_size >= WS_W) {
        hipLaunchKernelGGL(presplit_kernel, dim3(199), dim3(256), 0, stream,
                           Wq, Wk, Wv, Wc, (unsigned char*)d_ws);
        hipLaunchKernelGGL((mha_fused_kernel<1>), grid, block, 0, stream,
                           x, Wq, bq, Wk, bk, Wv, bv, Wc, bc,
                           (const unsigned char*)d_ws, out);
    } else {
        hipLaunchKernelGGL((mha_fused_kernel<0>), grid, block, 0, stream,
                           x, Wq, bq, Wk, bk, Wv, bv, Wc, bc,
                           (const unsigned char*)nullptr, out);
    }
}

// Round 8
// 881.497 us; speedup vs baseline: 1.1790x; 1.1790x over previous
//
#include <hip/hip_runtime.h>
#include <hip/hip_bf16.h>

// R8: R7 falsified "conflicts critical" (conflicts -10x, dur flat). R5->R6 delta was the
// inline x staging (~1000 VALU+ds_write instr/thread vs ~10 gloads). Merge proven best:
//   R5 MODE-2 staging (x+W fragment-linear ws images, pure gload, linear reads)
// + R7 swapped softmax (k-reduce = in-lane + 2 shfl) with P_STRIDE=216 (conflict-free)
// + single merged pre-kernel launch.
// Predicted: main ~680us, total ~900us, conflicts ~0.9e7, VALU ~41%, MFMA ~27%.

constexpr int T  = 6;
constexpr int S  = 66;    // 3*J
constexpr int IN = 256;
constexpr int H  = 8;
constexpr int D  = 32;
constexpr int J  = 22;
constexpr float NEG = -9e15f;
constexpr float INV_SQRT_D = 0.17677669529663688110f; // 1/sqrt(32)

// ---------------- LDS map (bytes), SMEM 49,152 -> 3 blocks/CU ------------------------
// stage (per 64-K chunk): x m01 tiles [8 hi|8 lo]x1KB @0..16,384 (fragment-linear);
//   x m2 tiles (rows 64..95): hi @16,384, lo @20,480 (zero-init once; rows 64/65/chunk);
//   W tiles [12 hi|12 lo]x1KB @24,576..49,152 (fragment-linear).
// attn persistent: qh/ql [66][36] @0/4,752; kh/kl @9,504/14,256 (end 19,008);
//   vTh/vTl bf16[32][104] @28,512/35,168 (208B rows, end 41,824);
//   inv f32[66] @41,824..42,088; aoT bf16[32][104] @42,096..48,752.
// overlays: Ph/Pl 216B-stride rows @0/14,256 (end 28,512, after q/k dead);
//   Wch/Wcl @28,512/35,168 (vT dead).
#define XM2H_OFF 16384
#define XM2L_OFF 20480
#define W_OFF    24576
#define W_LO     12288
#define QH_OFF   0
#define QL_OFF   4752
#define KH_OFF   9504
#define KL_OFF   14256
#define VTH_OFF  28512
#define VTL_OFF  35168
#define INV_OFF  41824
#define AOT_OFF  42096
#define PH_OFF   0
#define PL_OFF   14256
#define P_STRIDE 216
#define WCH_OFF  28512
#define WCL_OFF  35168
#define SMEM_BYTES 49152

// ws: 32 W images (h*4+chunk) of [12 hi|12 lo]x1KB = 24,576 -> 786,432;
// Wc image [hi 32x208B | lo 32x208B] = 13,312 -> 799,744;
// x images: per bt 4 chunks x 16,384 (rows 0..63) = 65,536 -> +201MB.
#define WSW_STRIDE 24576
#define WSWC_OFF   786432
#define WS_W       799744ull
#define XIMG_OFF   799744
#define XIMG_BT    65536
#define WS_FULL    (799744ull + 3072ull * 65536ull)

typedef float f32x4   __attribute__((ext_vector_type(4)));
typedef float f32x16  __attribute__((ext_vector_type(16)));
typedef short bf16x8  __attribute__((ext_vector_type(8)));
typedef short s4v     __attribute__((ext_vector_type(4)));

__device__ __forceinline__ unsigned cvtpk(float a, float b) {
    unsigned r;
    asm("v_cvt_pk_bf16_f32 %0, %1, %2" : "=v"(r) : "v"(a), "v"(b));
    return r;   // low16 = bf16(a), high16 = bf16(b), RNE
}
__device__ __forceinline__ float bfh2f(unsigned short h) {
    return __uint_as_float(((unsigned)h) << 16);
}
__device__ __forceinline__ void split2(float a, float b, unsigned& hi, unsigned& lo) {
    unsigned h = cvtpk(a, b);
    float ra = a - __uint_as_float(h << 16);
    float rb = b - __uint_as_float(h & 0xffff0000u);
    lo = cvtpk(ra, rb);
    hi = h;
}
__device__ __forceinline__ bf16x8 ld_bf16x8_a8(const short* p) {
    s4v a = *(const s4v*)p;
    s4v b = *(const s4v*)(p + 4);
    return __builtin_shufflevector(a, b, 0, 1, 2, 3, 4, 5, 6, 7);
}
__device__ __forceinline__ void gload16(const void* g, void* l) {
    __builtin_amdgcn_global_load_lds(
        (const __attribute__((address_space(1))) unsigned*)g,
        (__attribute__((address_space(3))) unsigned*)l, 16, 0, 0);
}

// ---------------- merged pre-kernel: W/Wc images (blocks 0..198) + x images ----------
__global__ __launch_bounds__(256)
void presplit_all(const float* __restrict__ Wq, const float* __restrict__ Wk,
                  const float* __restrict__ Wv, const float* __restrict__ Wc,
                  const float* __restrict__ x, unsigned char* __restrict__ ws)
{
    __shared__ __align__(16) unsigned char lds[16384];
    const int tid = threadIdx.x;
    if (blockIdx.x < 199) {
        int gid = blockIdx.x * 256 + tid;
        if (gid < 49152) {                     // 32 images x 96 rows x 16 col-groups
            int img = gid / 1536, u = gid - img * 1536;
            int row = u >> 4, c = u & 15, k0 = c << 2;
            int mat = row >> 5, dd = row & 31;
            int chunk = img & 3, hh = img >> 2;
            const float* Wm = (mat == 0) ? Wq : (mat == 1) ? Wk : Wv;
            float4 v = *(const float4*)(Wm + (size_t)(hh * 32 + dd) * IN + chunk * 64 + c * 4);
            uint2 hi, lo;
            split2(v.x, v.y, hi.x, lo.x);
            split2(v.z, v.w, hi.y, lo.y);
            int tile  = (mat << 2) + (k0 >> 4);
            int lanei = dd + (((k0 >> 3) & 1) << 5);
            int byte  = (tile << 10) + (lanei << 4) + ((k0 & 7) << 1);
            unsigned char* base = ws + (size_t)img * WSW_STRIDE;
            *(uint2*)(base + byte)        = hi;
            *(uint2*)(base + W_LO + byte) = lo;
        } else if (gid < 49152 + 1664) {       // Wc image: 32 rows x 52 dword cols
            int g2  = gid - 49152;
            int row = g2 / 52, cu = g2 - row * 52;
            int c0  = 2 * cu;
            float a = (row < 22 && c0     < 66) ? Wc[row * 66 + c0]     : 0.f;
            float b = (row < 22 && c0 + 1 < 66) ? Wc[row * 66 + c0 + 1] : 0.f;
            unsigned hi, lo;
            split2(a, b, hi, lo);
            *(unsigned*)(ws + WSWC_OFF + row * 208 + 4 * cu)        = hi;
            *(unsigned*)(ws + WSWC_OFF + 6656 + row * 208 + 4 * cu) = lo;
        }
    } else {
        // x rows 0..63 -> fragment-linear image, LDS-staged for coalesced 16B stores
        const int bid = blockIdx.x - 199;      // [0, 12288)
        const int chunk = bid & 3;
        const int bt = bid >> 2;
        const float* xg = x + (size_t)bt * S * IN + chunk * 64;
        for (int u = tid; u < 1024; u += 256) {     // rows 0..63 x 16 col-groups
            int s = u >> 4, c = u & 15;
            int rel = ((s << 7) + (c << 3)) ^ ((s & 7) << 4);
            float4 v = *(const float4*)(xg + (size_t)s * IN + c * 4);
            uint2 hi, lo;
            split2(v.x, v.y, hi.x, lo.x);
            split2(v.z, v.w, hi.y, lo.y);
            *(uint2*)(lds + rel)        = hi;
            *(uint2*)(lds + 8192 + rel) = lo;
        }
        __syncthreads();
        const int lane = tid & 63, wid = tid >> 6;
        unsigned char* img = ws + XIMG_OFF + (size_t)bt * XIMG_BT + chunk * 16384;
        for (int i = wid; i < 16; i += 4) {
            int comp = (i >= 8) ? 1 : 0;
            int ti = i - comp * 8;
            int mtile = ti >> 2, ks = ti & 3;
            int row = mtile * 32 + (lane & 31);
            int rel = ((row << 7) + (ks << 5) + ((lane >> 5) << 4)) ^ ((row & 7) << 4);
            uint4 v = *(const uint4*)(lds + comp * 8192 + rel);
            *(uint4*)(img + (i << 10) + (lane << 4)) = v;
        }
    }
}

// MODE: 0 = all inline, 1 = W/Wc presplit, 2 = W/Wc + x presplit (default)
template<int MODE>
__global__ __launch_bounds__(256, 3)
void mha_fused_kernel(const float* __restrict__ x,
                      const float* __restrict__ Wq, const float* __restrict__ bq,
                      const float* __restrict__ Wk, const float* __restrict__ bk,
                      const float* __restrict__ Wv, const float* __restrict__ bv,
                      const float* __restrict__ Wc, const float* __restrict__ bc,
                      const unsigned char* __restrict__ ws,
                      float* __restrict__ out)
{
    __shared__ __align__(16) unsigned char smem[SMEM_BYTES];

    const int tid = threadIdx.x;
    // bt-grouping XCD swizzle: 8 heads of one bt land on one XCD, adjacent in time.
    const int i0  = blockIdx.x;
    const int h   = (i0 >> 3) & 7;
    const int bt  = (i0 & 7) | ((i0 >> 6) << 3);   // bijective over [0,3072)

    const int wid  = tid >> 6;           // wave 0..3
    const int lane = tid & 63;
    const int l15  = lane & 15;
    const int quad = lane >> 4;

    // zero x-m2 tiles once (rows 66..95 stay zero; rows 64/65 rewritten per chunk)
    for (int u = tid; u < 512; u += 256)
        *(uint4*)(smem + XM2H_OFF + u * 16) = (uint4){0u, 0u, 0u, 0u};

    // ---------------- Phase 1: q,k,v projections via split-bf16 32x32x16 MFMA --------
    const f32x16 zacc = {0.f,0.f,0.f,0.f,0.f,0.f,0.f,0.f,0.f,0.f,0.f,0.f,0.f,0.f,0.f,0.f};
    f32x16 accs[3] = {zacc, zacc, zacc};

    const float* xg0 = x + (size_t)bt * S * IN;
    for (int chunk = 0; chunk < 4; ++chunk) {    // K = 4 x 64
        __syncthreads();
        const float* xg = xg0 + chunk * 64;
        if constexpr (MODE == 2) {
            const unsigned char* ximg = ws + XIMG_OFF + (size_t)bt * XIMG_BT + chunk * 16384;
            const unsigned char* wimg = ws + (size_t)((h << 2) | chunk) * WSW_STRIDE;
            for (int i = wid; i < 16; i += 4)
                gload16(ximg + (i << 10) + (lane << 4), smem + (i << 10));
            for (int i = wid; i < 24; i += 4)
                gload16(wimg + (i << 10) + (lane << 4), smem + W_OFF + (i << 10));
            if (tid < 32) {                      // rows 64,65 direct from x (L2-hot)
                int s = 64 + (tid >> 4), c = tid & 15;
                float4 v = *(const float4*)(xg + (size_t)s * IN + c * 4);
                uint2 hi, lo;
                split2(v.x, v.y, hi.x, lo.x);
                split2(v.z, v.w, hi.y, lo.y);
                int off = ((c >> 2) << 10) + (((s & 31) + (((c >> 1) & 1) << 5)) << 4)
                        + ((c & 1) << 3);
                *(uint2*)(smem + XM2H_OFF + off) = hi;
                *(uint2*)(smem + XM2L_OFF + off) = lo;
            }
        } else {
            if constexpr (MODE == 1) {
                const unsigned char* wimg = ws + (size_t)((h << 2) | chunk) * WSW_STRIDE;
                for (int i = wid; i < 24; i += 4)
                    gload16(wimg + (i << 10) + (lane << 4), smem + W_OFF + (i << 10));
            } else {
                for (int u = tid; u < 1536; u += 256) {   // W inline -> fragment-linear
                    int row = u >> 4, c = u & 15, k0 = c << 2;
                    int mat = row >> 5, dd2 = row & 31;
                    const float* Wm = (mat == 0) ? Wq : (mat == 1) ? Wk : Wv;
                    float4 v = *(const float4*)(Wm + (size_t)(h * 32 + dd2) * IN + chunk * 64 + c * 4);
                    uint2 hi, lo;
                    split2(v.x, v.y, hi.x, lo.x);
                    split2(v.z, v.w, hi.y, lo.y);
                    int tile  = (mat << 2) + (k0 >> 4);
                    int lanei = dd2 + (((k0 >> 3) & 1) << 5);
                    int byte  = (tile << 10) + (lanei << 4) + ((k0 & 7) << 1);
                    *(uint2*)(smem + W_OFF + byte)        = hi;
                    *(uint2*)(smem + W_OFF + W_LO + byte) = lo;
                }
            }
            // x inline -> fragment-linear (rows 0..65; 66..95 remain zero from init)
            for (int u = tid; u < 1536; u += 256) {
                int s = u >> 4, c = u & 15, k0 = c << 2;
                if (s >= 66) continue;
                float4 v = *(const float4*)(xg + (size_t)s * IN + c * 4);
                uint2 hi, lo;
                split2(v.x, v.y, hi.x, lo.x);
                split2(v.z, v.w, hi.y, lo.y);
                int ks = k0 >> 4, khalf = (k0 >> 3) & 1, b = (k0 & 7) << 1;
                int off = (ks << 10) + (((s & 31) + (khalf << 5)) << 4) + b;
                if (s < 64) {
                    int base = (s >> 5) * 4096 + off;
                    *(uint2*)(smem + base)        = hi;
                    *(uint2*)(smem + base + 8192) = lo;
                } else {
                    *(uint2*)(smem + XM2H_OFF + off) = hi;
                    *(uint2*)(smem + XM2L_OFF + off) = lo;
                }
            }
        }
        __syncthreads();

        #pragma unroll
        for (int t = 0; t < 3; ++t) {
            int p = wid + 4 * t;                 // p = mtile*3 + mat, over [0,9)
            if (p >= 9) break;                   // wave-uniform
            int mtile = p / 3, mat = p - mtile * 3;
            const unsigned char *xaH, *xaL;
            if (mtile < 2) { xaH = smem + mtile * 4096 + (lane << 4); xaL = xaH + 8192; }
            else           { xaH = smem + XM2H_OFF + (lane << 4);     xaL = xaH + 4096; }
            const unsigned char* wbH = smem + W_OFF + mat * 4096 + (lane << 4);
            #pragma unroll
            for (int ks = 0; ks < 4; ++ks) {
                bf16x8 ah = *(const bf16x8*)(xaH + (ks << 10));
                bf16x8 al = *(const bf16x8*)(xaL + (ks << 10));
                bf16x8 bh = *(const bf16x8*)(wbH + (ks << 10));
                bf16x8 bl = *(const bf16x8*)(wbH + (ks << 10) + W_LO);
                accs[t] = __builtin_amdgcn_mfma_f32_32x32x16_bf16(ah, bh, accs[t], 0, 0, 0);
                accs[t] = __builtin_amdgcn_mfma_f32_32x32x16_bf16(ah, bl, accs[t], 0, 0, 0);
                accs[t] = __builtin_amdgcn_mfma_f32_32x32x16_bf16(al, bh, accs[t], 0, 0, 0);
            }
        }
    }
    __syncthreads();   // stage dead; epilogue overwrites it

    // -------- Epilogue: q/k -> hi/lo [s][d]; v -> relu, hi/lo transposed [d][s] ------
    // 32x32 C/D layout: col = lane&31, row = (reg&3) + 8*(reg>>2) + 4*(lane>>5).
    {
        short* qh = (short*)(smem + QH_OFF); short* ql = (short*)(smem + QL_OFF);
        short* kh = (short*)(smem + KH_OFF); short* kl = (short*)(smem + KL_OFF);
        const int dd = lane & 31;
        const int half = lane >> 5;
        #pragma unroll
        for (int t = 0; t < 3; ++t) {
            int p = wid + 4 * t;
            if (p >= 9) break;
            int mtile = p / 3, mat = p - mtile * 3;
            const float* bias_p = (mat == 0) ? bq : (mat == 1) ? bk : bv;
            float bias = bias_p[h * 32 + dd];
            if (mat < 2) {
                short* bh_ = (mat == 0) ? qh : kh;
                short* bl_ = (mat == 0) ? ql : kl;
                #pragma unroll
                for (int g = 0; g < 4; ++g) {
                    int sb2 = mtile * 32 + half * 4 + 8 * g;
                    uint2 hi, lo;
                    split2(accs[t][4*g+0] + bias, accs[t][4*g+1] + bias, hi.x, lo.x);
                    split2(accs[t][4*g+2] + bias, accs[t][4*g+3] + bias, hi.y, lo.y);
                    unsigned hs[4] = { hi.x & 0xffffu, hi.x >> 16, hi.y & 0xffffu, hi.y >> 16 };
                    unsigned ls[4] = { lo.x & 0xffffu, lo.x >> 16, lo.y & 0xffffu, lo.y >> 16 };
                    #pragma unroll
                    for (int r = 0; r < 4; ++r) {
                        int s = sb2 + r;
                        if (s < 66) {
                            bh_[s * 36 + dd] = (short)hs[r];
                            bl_[s * 36 + dd] = (short)ls[r];
                        }
                    }
                }
            } else {
                #pragma unroll
                for (int g = 0; g < 4; ++g) {
                    int sb2 = mtile * 32 + half * 4 + 8 * g;
                    float vv[4];
                    #pragma unroll
                    for (int r = 0; r < 4; ++r) {
                        int s = sb2 + r;
                        vv[r] = (s < 66) ? fmaxf(accs[t][4*g+r] + bias, 0.f) : 0.f;
                    }
                    uint2 ph, pl;
                    split2(vv[0], vv[1], ph.x, pl.x);
                    split2(vv[2], vv[3], ph.y, pl.y);
                    *(uint2*)(smem + VTH_OFF + dd * 208 + 2 * sb2) = ph;
                    *(uint2*)(smem + VTL_OFF + dd * 208 + 2 * sb2) = pl;
                }
            }
        }
    }
    __syncthreads();

    // ------- Phase 3+4 fused, SWAPPED: scores^T = K·Q^T ------------------------------
    // a = k rows (mk strip), b = q rows (mq strip). Output: row k = mk*16+quad*4+reg,
    // col q = mq*16+l15. Per lane: one q, 20 k-values -> k-reduce = in-lane + shfl 16,32.
    {
        const short* qh = (const short*)(smem + QH_OFF);
        const short* ql = (const short*)(smem + QL_OFF);
        const short* kh = (const short*)(smem + KH_OFF);
        const short* kl = (const short*)(smem + KL_OFF);

        auto qk_mfma = [&](int mq, f32x4* acc) {
            int boff = (mq * 16 + l15) * 36 + quad * 8;
            bf16x8 bh = ld_bf16x8_a8(qh + boff);
            bf16x8 bl = ld_bf16x8_a8(ql + boff);
            #pragma unroll
            for (int mk = 0; mk < 5; ++mk) {
                int aoff = (mk * 16 + l15) * 36 + quad * 8;
                bf16x8 ah = ld_bf16x8_a8(kh + aoff);
                bf16x8 al = ld_bf16x8_a8(kl + aoff);
                f32x4 a = (f32x4){0.f, 0.f, 0.f, 0.f};
                a = __builtin_amdgcn_mfma_f32_16x16x32_bf16(ah, bh, a, 0, 0, 0);
                a = __builtin_amdgcn_mfma_f32_16x16x32_bf16(ah, bl, a, 0, 0, 0);
                a = __builtin_amdgcn_mfma_f32_16x16x32_bf16(al, bh, a, 0, 0, 0);
                acc[mk] = a;
            }
        };

        f32x4 accA[5], accB[5];
        qk_mfma(wid, accA);
        if (wid == 3) qk_mfma(4, accB);
        __syncthreads();   // all q/k reads done -> P may overlay q/k

        unsigned char* Ph = smem + PH_OFF;
        unsigned char* Pl = smem + PL_OFF;
        float* inv = (float*)(smem + INV_OFF);

        auto sm_store = [&](int mq, f32x4* acc) {
            const int q = mq * 16 + l15;
            float v[5][4];
            #pragma unroll
            for (int mk = 0; mk < 5; ++mk) {
                #pragma unroll
                for (int reg = 0; reg < 4; ++reg) {
                    int k = mk * 16 + quad * 4 + reg;
                    bool invalid = (k >= 66);
                    bool masked = (q < J && k >= 2 * J) || (q >= 2 * J && k < J);
                    float s = acc[mk][reg] * INV_SQRT_D;
                    v[mk][reg] = invalid ? -INFINITY : (masked ? 0.f : s);
                }
            }
            float mm = -INFINITY;
            #pragma unroll
            for (int mk = 0; mk < 5; ++mk)
                #pragma unroll
                for (int reg = 0; reg < 4; ++reg) mm = fmaxf(mm, v[mk][reg]);
            mm = fmaxf(mm, __shfl_xor(mm, 16));
            mm = fmaxf(mm, __shfl_xor(mm, 32));
            const float thr = mm / 9.0f;
            float rm = -INFINITY;
            #pragma unroll
            for (int mk = 0; mk < 5; ++mk) {
                #pragma unroll
                for (int reg = 0; reg < 4; ++reg) {
                    float sv = v[mk][reg];
                    float pr = (fabsf(sv) <= thr) ? NEG : sv;   // -INF sentinels stay below
                    v[mk][reg] = pr;
                    rm = fmaxf(rm, pr);
                }
            }
            rm = fmaxf(rm, __shfl_xor(rm, 16));
            rm = fmaxf(rm, __shfl_xor(rm, 32));
            float e[5][4], lsum = 0.f;
            #pragma unroll
            for (int mk = 0; mk < 5; ++mk) {
                #pragma unroll
                for (int reg = 0; reg < 4; ++reg) {
                    float ev = __expf(v[mk][reg] - rm);   // -INF -> 0
                    e[mk][reg] = ev;
                    lsum += ev;
                }
            }
            lsum += __shfl_xor(lsum, 16);
            lsum += __shfl_xor(lsum, 32);
            if (q < 66) {
                #pragma unroll
                for (int mk = 0; mk < 5; ++mk) {
                    unsigned h0 = cvtpk(e[mk][0], e[mk][1]);
                    unsigned h1 = cvtpk(e[mk][2], e[mk][3]);
                    uint2 hi = {h0, h1}, lo;
                    lo.x = cvtpk(e[mk][0] - bfh2f((unsigned short)h0),
                                 e[mk][1] - bfh2f((unsigned short)(h0 >> 16)));
                    lo.y = cvtpk(e[mk][2] - bfh2f((unsigned short)h1),
                                 e[mk][3] - bfh2f((unsigned short)(h1 >> 16)));
                    int kb = (mk * 16 + quad * 4) * 2;
                    *(uint2*)(Ph + q * P_STRIDE + kb) = hi;
                    *(uint2*)(Pl + q * P_STRIDE + kb) = lo;
                }
                if (quad == 0) inv[q] = 1.0f / lsum;
            }
        };

        sm_store(wid, accA);
        if (wid == 3) sm_store(4, accB);

        // zero P cols 80..95 (bytes 160..191) rows 0..65, both components
        for (int u = tid; u < 528; u += 256) {
            int comp = u >= 264 ? 1 : 0, rem = u - comp * 264;
            int row = rem >> 2, slot = rem & 3;
            *(uint2*)(smem + (comp ? PL_OFF : PH_OFF) + row * P_STRIDE + 160 + slot * 8)
                = (uint2){0u, 0u};
        }
    }
    __syncthreads();

    // ---------------- Phase 5: aoT = (P @ v)^T * inv, bf16-hi, via MFMA --------------
    {
        const short* Ph = (const short*)(smem + PH_OFF);
        const short* Pl = (const short*)(smem + PL_OFF);
        const short* vh = (const short*)(smem + VTH_OFF);
        const short* vl = (const short*)(smem + VTL_OFF);
        const float* inv = (const float*)(smem + INV_OFF);
        for (int t = 0; t < 3; ++t) {
            int tt = wid + 4 * t;
            if (tt >= 10) break;
            int mq = tt >> 1, nd = tt & 1;
            f32x4 acc = (f32x4){0.f, 0.f, 0.f, 0.f};
            #pragma unroll
            for (int ks = 0; ks < 3; ++ks) {
                // P rows at 216B stride (108 shorts): 8B-aligned -> b64-pair loads
                bf16x8 a   = ld_bf16x8_a8(Ph + (mq * 16 + l15) * 108 + ks * 32 + quad * 8);
                bf16x8 al8 = ld_bf16x8_a8(Pl + (mq * 16 + l15) * 108 + ks * 32 + quad * 8);
                bf16x8 b   = *(const bf16x8*)(vh + (nd * 16 + l15) * 104 + ks * 32 + quad * 8);
                bf16x8 bl8 = *(const bf16x8*)(vl + (nd * 16 + l15) * 104 + ks * 32 + quad * 8);
                acc = __builtin_amdgcn_mfma_f32_16x16x32_bf16(a, b, acc, 0, 0, 0);
                acc = __builtin_amdgcn_mfma_f32_16x16x32_bf16(al8, b, acc, 0, 0, 0);
                acc = __builtin_amdgcn_mfma_f32_16x16x32_bf16(a, bl8, acc, 0, 0, 0);
            }
            int dd = nd * 16 + l15, sbase = mq * 16 + quad * 4;
            float o[4];
            #pragma unroll
            for (int reg = 0; reg < 4; ++reg) {
                int qs = sbase + reg;
                o[reg] = (qs < 66) ? acc[reg] * inv[qs] : 0.f;
            }
            uint2 pk;
            pk.x = cvtpk(o[0], o[1]);
            pk.y = cvtpk(o[2], o[3]);
            *(uint2*)(smem + AOT_OFF + dd * 208 + 2 * sbase) = pk;
        }
        // zero aoT cols 80..103
        for (int u = tid; u < 384; u += 256) {
            int row = u / 12, kcol = 80 + 2 * (u % 12);
            *(unsigned*)(smem + AOT_OFF + row * 208 + 2 * kcol) = 0u;
        }
    }
    __syncthreads();

    // ---------------- Stage Wc hi/lo (overlays dead vT) ------------------------------
    if constexpr (MODE >= 1) {
        const unsigned char* wc = ws + WSWC_OFF;   // pre-built 13,312B image
        for (int i = wid; i < 13; i += 4)
            gload16(wc + (i << 10) + (lane << 4), smem + WCH_OFF + (i << 10));
    } else {
        for (int u = tid; u < 726; u += 256) {           // 22 rows x 33 float2
            int row = u / 33, cp = u - row * 33;
            float2 w = *(const float2*)(Wc + row * 66 + 2 * cp);
            unsigned hi, lo;
            split2(w.x, w.y, hi, lo);
            *(unsigned*)(smem + WCH_OFF + row * 208 + 4 * cp) = hi;
            *(unsigned*)(smem + WCL_OFF + row * 208 + 4 * cp) = lo;
        }
        for (int u = tid; u < 836; u += 256) {           // zero cols 66..103, rows 0..21
            int comp = u >= 418 ? 1 : 0, rem = comp ? u - 418 : u;
            int row = rem / 19, kcol = 66 + 2 * (rem % 19);
            *(unsigned*)(smem + (comp ? WCL_OFF : WCH_OFF) + row * 208 + 2 * kcol) = 0u;
        }
    }
    __syncthreads();

    // ---------------- Phase 6: out = Wc @ ao + bc via MFMA ---------------------------
    {
        const short* Wch = (const short*)(smem + WCH_OFF);
        const short* Wcl = (const short*)(smem + WCL_OFF);
        const short* aoT = (const short*)(smem + AOT_OFF);
        int mj = wid >> 1, nd = wid & 1;
        f32x4 acc = (f32x4){0.f, 0.f, 0.f, 0.f};
        #pragma unroll
        for (int ks = 0; ks < 3; ++ks) {
            bf16x8 a   = *(const bf16x8*)(Wch + (mj * 16 + l15) * 104 + ks * 32 + quad * 8);
            bf16x8 al8 = *(const bf16x8*)(Wcl + (mj * 16 + l15) * 104 + ks * 32 + quad * 8);
            bf16x8 b   = *(const bf16x8*)(aoT + (nd * 16 + l15) * 104 + ks * 32 + quad * 8);
            acc = __builtin_amdgcn_mfma_f32_16x16x32_bf16(a, b, acc, 0, 0, 0);
            acc = __builtin_amdgcn_mfma_f32_16x16x32_bf16(al8, b, acc, 0, 0, 0);
        }
        int dd = nd * 16 + l15;
        #pragma unroll
        for (int reg = 0; reg < 4; ++reg) {
            int j = mj * 16 + quad * 4 + reg;
            if (j < 22) {
                size_t o = (size_t)(bt * J + j) * (H * D) + h * 32 + dd;
                out[o] = acc[reg] + bc[j];
            }
        }
    }
}

extern "C" void kernel_launch(void* const* d_in, const int* in_sizes, int n_in,
                              void* d_out, int out_size, void* d_ws, size_t ws_size,
                              hipStream_t stream) {
    const float* x  = (const float*)d_in[0];
    const float* Wq = (const float*)d_in[1];
    const float* bq = (const float*)d_in[2];
    const float* Wk = (const float*)d_in[3];
    const float* bk = (const float*)d_in[4];
    const float* Wv = (const float*)d_in[5];
    const float* bv = (const float*)d_in[6];
    const float* Wc = (const float*)d_in[7];
    const float* bc = (const float*)d_in[8];
    float* out = (float*)d_out;

    const int B = 512;
    dim3 grid(B * T * H), block(256);
    if (d_ws != nullptr && ws_size >= WS_FULL) {
        hipLaunchKernelGGL(presplit_all, dim3(199 + 12288), dim3(256), 0, stream,
                           Wq, Wk, Wv, Wc, x, (unsigned char*)d_ws);
        hipLaunchKernelGGL((mha_fused_kernel<2>), grid, block, 0, stream,
                           x, Wq, bq, Wk, bk, Wv, bv, Wc, bc,
                           (const unsigned char*)d_ws, out);
    } else if (d_ws != nullptr && ws_size >= WS_W) {
        hipLaunchKernelGGL(presplit_all, dim3(199), dim3(256), 0, stream,
                           Wq, Wk, Wv, Wc, x, (unsigned char*)d_ws);
        hipLaunchKernelGGL((mha_fused_kernel<1>), grid, block, 0, stream,
                           x, Wq, bq, Wk, bk, Wv, bv, Wc, bc,
                           (const unsigned char*)d_ws, out);
    } else {
        hipLaunchKernelGGL((mha_fused_kernel<0>), grid, block, 0, stream,
                           x, Wq, bq, Wk, bk, Wv, bv, Wc, bc,
                           (const unsigned char*)nullptr, out);
    }
}

// Round 9
// 806.050 us; speedup vs baseline: 1.2894x; 1.0936x over previous
//
#include <hip/hip_runtime.h>
#include <hip/hip_bf16.h>

// R9 theory: occupancy-bound (3 blocks/CU @49KB LDS; VALU 42 + MFMA 30 + ~27% stall).
// 1) W fragments global->VGPR direct from pre-split images (per-wave-private; L2-hot)
//    -> stage LDS = x only (24,576B).
// 2) Attn buffers 64-col (stride 136B, conflict-free); k,s in {64,65} handled as exact
//    f32 VALU rank-2 tails with tiny side arrays -> attn LDS 32,576B.
// SMEM 32,576 -> 32,768 rounded -> exactly 5 blocks/CU (20 waves). Phase5 MFMAs 9->6
// per product; Wc stage + 1 barrier + all zero-fill loops deleted.
// Predicted: Occupancy ~55%, main ~500us, total ~750us, MFMA ~34%, conflicts <1e7.

constexpr int T  = 6;
constexpr int S  = 66;    // 3*J
constexpr int IN = 256;
constexpr int H  = 8;
constexpr int D  = 32;
constexpr int J  = 22;
constexpr float NEG = -9e15f;
constexpr float INV_SQRT_D = 0.17677669529663688110f; // 1/sqrt(32)

// ---------------- LDS map (bytes), SMEM 32,576 -> 5 blocks/CU ------------------------
// stage (per 64-K chunk): x m01 frag tiles [8 hi|8 lo]x1KB @0..16,384;
//   xm2 hi @16,384, lo @20,480 (zero-init once; rows 64/65 per chunk). End 24,576.
// attn: qh/ql [66][36] @0/4,752; kh/kl @9,504/14,256 (end 19,008)
//   P (overlays q/k after QK^T): Ph@0, Pl@8,976 (66 rows x 136B); P64 f32[66][2]@17,952;
//   inv f32[66]@18,480 (end 18,744)
//   vT: hi@19,008, lo@23,360 (32 x 136B); v64 f32[32][2]@27,712 (end 27,968)
//   aoT @27,968 (32 x 136B); ao64 f32[32][2]@32,320 (end 32,576)
#define XM2H_OFF 16384
#define XM2L_OFF 20480
#define QH_OFF   0
#define QL_OFF   4752
#define KH_OFF   9504
#define KL_OFF   14256
#define PH_OFF   0
#define PL_OFF   8976
#define P64_OFF  17952
#define INV_OFF  18480
#define VTH_OFF  19008
#define VTL_OFF  23360
#define V64_OFF  27712
#define AOT_OFF  27968
#define AO64_OFF 32320
#define SMEM_BYTES 32576
#define PV_ROW   68          // row stride in shorts (136 B)

// ws: 32 W images (h*4+chunk) of [12 hi|12 lo]x1KB = 24,576 -> 786,432;
// Wc frag image [4 hi|4 lo]x1KB = 8,192 -> 794,624;
// x images: per bt 4 chunks x 16,384 = 65,536 -> +201MB.
#define WSW_STRIDE 24576
#define W_LO       12288
#define WSWC_OFF   786432
#define WS_W       794624ull
#define XIMG_OFF   794624
#define XIMG_BT    65536
#define WS_FULL    (794624ull + 3072ull * 65536ull)

typedef float f32x4   __attribute__((ext_vector_type(4)));
typedef float f32x16  __attribute__((ext_vector_type(16)));
typedef short bf16x8  __attribute__((ext_vector_type(8)));
typedef short s4v     __attribute__((ext_vector_type(4)));

__device__ __forceinline__ unsigned cvtpk(float a, float b) {
    unsigned r;
    asm("v_cvt_pk_bf16_f32 %0, %1, %2" : "=v"(r) : "v"(a), "v"(b));
    return r;   // low16 = bf16(a), high16 = bf16(b), RNE
}
__device__ __forceinline__ float bfh2f(unsigned short h) {
    return __uint_as_float(((unsigned)h) << 16);
}
__device__ __forceinline__ void split2(float a, float b, unsigned& hi, unsigned& lo) {
    unsigned h = cvtpk(a, b);
    float ra = a - __uint_as_float(h << 16);
    float rb = b - __uint_as_float(h & 0xffff0000u);
    lo = cvtpk(ra, rb);
    hi = h;
}
__device__ __forceinline__ bf16x8 ld_bf16x8_a8(const short* p) {
    s4v a = *(const s4v*)p;
    s4v b = *(const s4v*)(p + 4);
    return __builtin_shufflevector(a, b, 0, 1, 2, 3, 4, 5, 6, 7);
}
__device__ __forceinline__ void gload16(const void* g, void* l) {
    __builtin_amdgcn_global_load_lds(
        (const __attribute__((address_space(1))) unsigned*)g,
        (__attribute__((address_space(3))) unsigned*)l, 16, 0, 0);
}

// ---------------- merged pre-kernel: W images + Wc frag image + x images -------------
__global__ __launch_bounds__(256)
void presplit_all(const float* __restrict__ Wq, const float* __restrict__ Wk,
                  const float* __restrict__ Wv, const float* __restrict__ Wc,
                  const float* __restrict__ x, unsigned char* __restrict__ ws)
{
    __shared__ __align__(16) unsigned char lds[16384];
    const int tid = threadIdx.x;
    if (blockIdx.x < 199) {
        int gid = blockIdx.x * 256 + tid;
        if (gid < 49152) {                     // 32 W images x 96 rows x 16 col-groups
            int img = gid / 1536, u = gid - img * 1536;
            int row = u >> 4, c = u & 15, k0 = c << 2;
            int mat = row >> 5, dd = row & 31;
            int chunk = img & 3, hh = img >> 2;
            const float* Wm = (mat == 0) ? Wq : (mat == 1) ? Wk : Wv;
            float4 v = *(const float4*)(Wm + (size_t)(hh * 32 + dd) * IN + chunk * 64 + c * 4);
            uint2 hi, lo;
            split2(v.x, v.y, hi.x, lo.x);
            split2(v.z, v.w, hi.y, lo.y);
            int tile  = (mat << 2) + (k0 >> 4);
            int lanei = dd + (((k0 >> 3) & 1) << 5);
            int byte  = (tile << 10) + (lanei << 4) + ((k0 & 7) << 1);
            unsigned char* base = ws + (size_t)img * WSW_STRIDE;
            *(uint2*)(base + byte)        = hi;
            *(uint2*)(base + W_LO + byte) = lo;
        } else if (gid < 49152 + 1024) {       // Wc frag image: 32 rows x 32 col-pairs
            int g2  = gid - 49152;
            int row = g2 >> 5, cu = g2 & 31;
            int k0  = 2 * cu;                  // cols 0..63
            float a = (row < 22) ? Wc[row * 66 + k0]     : 0.f;
            float b = (row < 22) ? Wc[row * 66 + k0 + 1] : 0.f;
            unsigned hi, lo;
            split2(a, b, hi, lo);
            int tile = (row >> 4) * 2 + (k0 >> 5);
            int byte = (tile << 10) + (((row & 15) + 16 * ((k0 >> 3) & 3)) << 4)
                     + ((k0 & 7) << 1);
            *(unsigned*)(ws + WSWC_OFF + byte)        = hi;
            *(unsigned*)(ws + WSWC_OFF + 4096 + byte) = lo;
        }
    } else {
        // x rows 0..63 -> fragment-linear image (unchanged from R8)
        const int bid = blockIdx.x - 199;      // [0, 12288)
        const int chunk = bid & 3;
        const int bt = bid >> 2;
        const float* xg = x + (size_t)bt * S * IN + chunk * 64;
        for (int u = tid; u < 1024; u += 256) {
            int s = u >> 4, c = u & 15;
            int rel = ((s << 7) + (c << 3)) ^ ((s & 7) << 4);
            float4 v = *(const float4*)(xg + (size_t)s * IN + c * 4);
            uint2 hi, lo;
            split2(v.x, v.y, hi.x, lo.x);
            split2(v.z, v.w, hi.y, lo.y);
            *(uint2*)(lds + rel)        = hi;
            *(uint2*)(lds + 8192 + rel) = lo;
        }
        __syncthreads();
        const int lane = tid & 63, wid = tid >> 6;
        unsigned char* img = ws + XIMG_OFF + (size_t)bt * XIMG_BT + chunk * 16384;
        for (int i = wid; i < 16; i += 4) {
            int comp = (i >= 8) ? 1 : 0;
            int ti = i - comp * 8;
            int mtile = ti >> 2, ks = ti & 3;
            int row = mtile * 32 + (lane & 31);
            int rel = ((row << 7) + (ks << 5) + ((lane >> 5) << 4)) ^ ((row & 7) << 4);
            uint4 v = *(const uint4*)(lds + comp * 8192 + rel);
            *(uint4*)(img + (i << 10) + (lane << 4)) = v;
        }
    }
}

// MODE: 0 = all inline, 1 = W/Wc images + x inline, 2 = full images (default)
template<int MODE>
__global__ __launch_bounds__(256, 5)
void mha_fused_kernel(const float* __restrict__ x,
                      const float* __restrict__ Wq, const float* __restrict__ bq,
                      const float* __restrict__ Wk, const float* __restrict__ bk,
                      const float* __restrict__ Wv, const float* __restrict__ bv,
                      const float* __restrict__ Wc, const float* __restrict__ bc,
                      const unsigned char* __restrict__ ws,
                      float* __restrict__ out)
{
    __shared__ __align__(16) unsigned char smem[SMEM_BYTES];

    const int tid = threadIdx.x;
    // bt-grouping XCD swizzle: 8 heads of one bt land on one XCD, adjacent in time.
    const int i0  = blockIdx.x;
    const int h   = (i0 >> 3) & 7;
    const int bt  = (i0 & 7) | ((i0 >> 6) << 3);   // bijective over [0,3072)

    const int wid  = tid >> 6;           // wave 0..3
    const int lane = tid & 63;
    const int l15  = lane & 15;
    const int quad = lane >> 4;

    // zero xm2 tiles once (rows 66..95 stay zero; rows 64/65 rewritten per chunk)
    for (int u = tid; u < 512; u += 256)
        *(uint4*)(smem + XM2H_OFF + u * 16) = (uint4){0u, 0u, 0u, 0u};

    // ---------------- Phase 1: q,k,v projections; W fragments global->VGPR -----------
    const f32x16 zacc = {0.f,0.f,0.f,0.f,0.f,0.f,0.f,0.f,0.f,0.f,0.f,0.f,0.f,0.f,0.f,0.f};
    f32x16 accs[3] = {zacc, zacc, zacc};

    const float* xg0 = x + (size_t)bt * S * IN;
    for (int chunk = 0; chunk < 4; ++chunk) {    // K = 4 x 64
        __syncthreads();
        const float* xg = xg0 + chunk * 64;
        const unsigned char* wimg = ws + (size_t)((h << 2) | chunk) * WSW_STRIDE;
        if constexpr (MODE == 2) {
            const unsigned char* ximg = ws + XIMG_OFF + (size_t)bt * XIMG_BT + chunk * 16384;
            for (int i = wid; i < 16; i += 4)
                gload16(ximg + (i << 10) + (lane << 4), smem + (i << 10));
            if (tid < 32) {                      // rows 64,65 direct from x (L2-hot)
                int s = 64 + (tid >> 4), c = tid & 15;
                float4 v = *(const float4*)(xg + (size_t)s * IN + c * 4);
                uint2 hi, lo;
                split2(v.x, v.y, hi.x, lo.x);
                split2(v.z, v.w, hi.y, lo.y);
                int off = ((c >> 2) << 10) + (((s & 31) + (((c >> 1) & 1) << 5)) << 4)
                        + ((c & 1) << 3);
                *(uint2*)(smem + XM2H_OFF + off) = hi;
                *(uint2*)(smem + XM2L_OFF + off) = lo;
            }
        } else {
            // x inline -> fragment-linear (rows 0..65; 66..95 remain zero from init)
            for (int u = tid; u < 1536; u += 256) {
                int s = u >> 4, c = u & 15, k0 = c << 2;
                if (s >= 66) continue;
                float4 v = *(const float4*)(xg + (size_t)s * IN + c * 4);
                uint2 hi, lo;
                split2(v.x, v.y, hi.x, lo.x);
                split2(v.z, v.w, hi.y, lo.y);
                int ks = k0 >> 4, khalf = (k0 >> 3) & 1, b = (k0 & 7) << 1;
                int off = (ks << 10) + (((s & 31) + (khalf << 5)) << 4) + b;
                if (s < 64) {
                    int base = (s >> 5) * 4096 + off;
                    *(uint2*)(smem + base)        = hi;
                    *(uint2*)(smem + base + 8192) = lo;
                } else {
                    *(uint2*)(smem + XM2H_OFF + off) = hi;
                    *(uint2*)(smem + XM2L_OFF + off) = lo;
                }
            }
        }
        __syncthreads();

        #pragma unroll
        for (int t = 0; t < 3; ++t) {
            int p = wid + 4 * t;                 // p = mtile*3 + mat, over [0,9)
            if (p >= 9) break;                   // wave-uniform
            int mtile = p / 3, mat = p - mtile * 3;
            const unsigned char *xaH, *xaL;
            if (mtile < 2) { xaH = smem + mtile * 4096 + (lane << 4); xaL = xaH + 8192; }
            else           { xaH = smem + XM2H_OFF + (lane << 4);     xaL = xaH + 4096; }
            #pragma unroll
            for (int ks = 0; ks < 4; ++ks) {
                bf16x8 bh, bl;
                if constexpr (MODE >= 1) {
                    const unsigned char* wt = wimg + (((mat * 4 + ks)) << 10) + (lane << 4);
                    bh = *(const bf16x8*)(wt);
                    bl = *(const bf16x8*)(wt + W_LO);
                } else {
                    const float* Wm = (mat == 0) ? Wq : (mat == 1) ? Wk : Wv;
                    const float* wrow = Wm + (size_t)(h * 32 + (lane & 31)) * IN
                                      + chunk * 64 + ks * 16 + (lane >> 5) * 8;
                    float4 w0 = *(const float4*)wrow, w1 = *(const float4*)(wrow + 4);
                    uint4 uh, ul;
                    split2(w0.x, w0.y, uh.x, ul.x);
                    split2(w0.z, w0.w, uh.y, ul.y);
                    split2(w1.x, w1.y, uh.z, ul.z);
                    split2(w1.z, w1.w, uh.w, ul.w);
                    bh = *(bf16x8*)&uh;
                    bl = *(bf16x8*)&ul;
                }
                bf16x8 ah = *(const bf16x8*)(xaH + (ks << 10));
                bf16x8 al = *(const bf16x8*)(xaL + (ks << 10));
                accs[t] = __builtin_amdgcn_mfma_f32_32x32x16_bf16(ah, bh, accs[t], 0, 0, 0);
                accs[t] = __builtin_amdgcn_mfma_f32_32x32x16_bf16(ah, bl, accs[t], 0, 0, 0);
                accs[t] = __builtin_amdgcn_mfma_f32_32x32x16_bf16(al, bh, accs[t], 0, 0, 0);
            }
        }
    }
    __syncthreads();   // stage dead; epilogue overwrites it

    // -------- Epilogue: q/k -> hi/lo [s][d]; v -> relu, transposed [d][s] + v64 ------
    // 32x32 C/D layout: col = lane&31, row = (reg&3) + 8*(reg>>2) + 4*(lane>>5).
    {
        short* qh = (short*)(smem + QH_OFF); short* ql = (short*)(smem + QL_OFF);
        short* kh = (short*)(smem + KH_OFF); short* kl = (short*)(smem + KL_OFF);
        const int dd = lane & 31;
        const int half = lane >> 5;
        #pragma unroll
        for (int t = 0; t < 3; ++t) {
            int p = wid + 4 * t;
            if (p >= 9) break;
            int mtile = p / 3, mat = p - mtile * 3;
            const float* bias_p = (mat == 0) ? bq : (mat == 1) ? bk : bv;
            float bias = bias_p[h * 32 + dd];
            if (mat < 2) {
                short* bh_ = (mat == 0) ? qh : kh;
                short* bl_ = (mat == 0) ? ql : kl;
                #pragma unroll
                for (int g = 0; g < 4; ++g) {
                    int sb2 = mtile * 32 + half * 4 + 8 * g;
                    uint2 hi, lo;
                    split2(accs[t][4*g+0] + bias, accs[t][4*g+1] + bias, hi.x, lo.x);
                    split2(accs[t][4*g+2] + bias, accs[t][4*g+3] + bias, hi.y, lo.y);
                    unsigned hs[4] = { hi.x & 0xffffu, hi.x >> 16, hi.y & 0xffffu, hi.y >> 16 };
                    unsigned ls[4] = { lo.x & 0xffffu, lo.x >> 16, lo.y & 0xffffu, lo.y >> 16 };
                    #pragma unroll
                    for (int r = 0; r < 4; ++r) {
                        int s = sb2 + r;
                        if (s < 66) {
                            bh_[s * 36 + dd] = (short)hs[r];
                            bl_[s * 36 + dd] = (short)ls[r];
                        }
                    }
                }
            } else {
                #pragma unroll
                for (int g = 0; g < 4; ++g) {
                    int sb2 = mtile * 32 + half * 4 + 8 * g;
                    float vv[4];
                    #pragma unroll
                    for (int r = 0; r < 4; ++r) {
                        int s = sb2 + r;
                        vv[r] = (s < 66) ? fmaxf(accs[t][4*g+r] + bias, 0.f) : 0.f;
                    }
                    if (sb2 < 64) {
                        uint2 ph, pl;
                        split2(vv[0], vv[1], ph.x, pl.x);
                        split2(vv[2], vv[3], ph.y, pl.y);
                        *(uint2*)(smem + VTH_OFF + dd * 136 + 2 * sb2) = ph;
                        *(uint2*)(smem + VTL_OFF + dd * 136 + 2 * sb2) = pl;
                    } else if (sb2 == 64) {    // mtile==2, half==0, g==0: s=64,65 (f32)
                        *(float2*)(smem + V64_OFF + dd * 8) = (float2){vv[0], vv[1]};
                    }
                }
            }
        }
    }
    __syncthreads();

    // ------- Phase 3+4 fused, SWAPPED: scores^T = K·Q^T + in-reg softmax -------------
    {
        const short* qh = (const short*)(smem + QH_OFF);
        const short* ql = (const short*)(smem + QL_OFF);
        const short* kh = (const short*)(smem + KH_OFF);
        const short* kl = (const short*)(smem + KL_OFF);

        auto qk_mfma = [&](int mq, f32x4* acc) {
            int boff = (mq * 16 + l15) * 36 + quad * 8;
            bf16x8 bh = ld_bf16x8_a8(qh + boff);
            bf16x8 bl = ld_bf16x8_a8(ql + boff);
            #pragma unroll
            for (int mk = 0; mk < 5; ++mk) {
                int aoff = (mk * 16 + l15) * 36 + quad * 8;
                bf16x8 ah = ld_bf16x8_a8(kh + aoff);
                bf16x8 al = ld_bf16x8_a8(kl + aoff);
                f32x4 a = (f32x4){0.f, 0.f, 0.f, 0.f};
                a = __builtin_amdgcn_mfma_f32_16x16x32_bf16(ah, bh, a, 0, 0, 0);
                a = __builtin_amdgcn_mfma_f32_16x16x32_bf16(ah, bl, a, 0, 0, 0);
                a = __builtin_amdgcn_mfma_f32_16x16x32_bf16(al, bh, a, 0, 0, 0);
                acc[mk] = a;
            }
        };

        f32x4 accA[5], accB[5];
        qk_mfma(wid, accA);
        if (wid == 3) qk_mfma(4, accB);
        __syncthreads();   // all q/k reads done -> P may overlay q/k

        unsigned char* Ph = smem + PH_OFF;
        unsigned char* Pl = smem + PL_OFF;
        float* inv = (float*)(smem + INV_OFF);

        auto sm_store = [&](int mq, f32x4* acc) {
            const int q = mq * 16 + l15;
            float v[5][4];
            #pragma unroll
            for (int mk = 0; mk < 5; ++mk) {
                #pragma unroll
                for (int reg = 0; reg < 4; ++reg) {
                    int k = mk * 16 + quad * 4 + reg;
                    bool invalid = (k >= 66);
                    bool masked = (q < J && k >= 2 * J) || (q >= 2 * J && k < J);
                    float s = acc[mk][reg] * INV_SQRT_D;
                    v[mk][reg] = invalid ? -INFINITY : (masked ? 0.f : s);
                }
            }
            float mm = -INFINITY;
            #pragma unroll
            for (int mk = 0; mk < 5; ++mk)
                #pragma unroll
                for (int reg = 0; reg < 4; ++reg) mm = fmaxf(mm, v[mk][reg]);
            mm = fmaxf(mm, __shfl_xor(mm, 16));
            mm = fmaxf(mm, __shfl_xor(mm, 32));
            const float thr = mm / 9.0f;
            float rm = -INFINITY;
            #pragma unroll
            for (int mk = 0; mk < 5; ++mk) {
                #pragma unroll
                for (int reg = 0; reg < 4; ++reg) {
                    float sv = v[mk][reg];
                    float pr = (fabsf(sv) <= thr) ? NEG : sv;   // -INF sentinels stay below
                    v[mk][reg] = pr;
                    rm = fmaxf(rm, pr);
                }
            }
            rm = fmaxf(rm, __shfl_xor(rm, 16));
            rm = fmaxf(rm, __shfl_xor(rm, 32));
            float e[5][4], lsum = 0.f;
            #pragma unroll
            for (int mk = 0; mk < 5; ++mk) {
                #pragma unroll
                for (int reg = 0; reg < 4; ++reg) {
                    float ev = __expf(v[mk][reg] - rm);   // -INF -> 0
                    e[mk][reg] = ev;
                    lsum += ev;
                }
            }
            lsum += __shfl_xor(lsum, 16);
            lsum += __shfl_xor(lsum, 32);
            if (q < 66) {
                #pragma unroll
                for (int mk = 0; mk < 4; ++mk) {       // cols 0..63 packed bf16 hi/lo
                    unsigned h0 = cvtpk(e[mk][0], e[mk][1]);
                    unsigned h1 = cvtpk(e[mk][2], e[mk][3]);
                    uint2 hi = {h0, h1}, lo;
                    lo.x = cvtpk(e[mk][0] - bfh2f((unsigned short)h0),
                                 e[mk][1] - bfh2f((unsigned short)(h0 >> 16)));
                    lo.y = cvtpk(e[mk][2] - bfh2f((unsigned short)h1),
                                 e[mk][3] - bfh2f((unsigned short)(h1 >> 16)));
                    int kb = mk * 32 + quad * 8;
                    *(uint2*)(Ph + q * 136 + kb) = hi;
                    *(uint2*)(Pl + q * 136 + kb) = lo;
                }
                if (quad == 0) {                        // cols 64,65 exact f32 + inv
                    *(float2*)(smem + P64_OFF + q * 8) = (float2){e[4][0], e[4][1]};
                    inv[q] = 1.0f / lsum;
                }
            }
        };

        sm_store(wid, accA);
        if (wid == 3) sm_store(4, accB);
    }
    __syncthreads();

    // ------- Phase 5: aoT = (P @ v)^T * inv; MFMA cols 0..63 + f32 tail k=64,65 ------
    {
        const short* Ph = (const short*)(smem + PH_OFF);
        const short* Pl = (const short*)(smem + PL_OFF);
        const short* vh = (const short*)(smem + VTH_OFF);
        const short* vl = (const short*)(smem + VTL_OFF);
        const float* inv = (const float*)(smem + INV_OFF);
        for (int t = 0; t < 3; ++t) {
            int tt = wid + 4 * t;
            if (tt >= 10) break;
            int mq = tt >> 1, nd = tt & 1;
            int arow = (mq * 16 + l15) * PV_ROW;
            int brow = (nd * 16 + l15) * PV_ROW;
            f32x4 acc = (f32x4){0.f, 0.f, 0.f, 0.f};
            #pragma unroll
            for (int ks = 0; ks < 2; ++ks) {
                bf16x8 a   = ld_bf16x8_a8(Ph + arow + ks * 32 + quad * 8);
                bf16x8 al8 = ld_bf16x8_a8(Pl + arow + ks * 32 + quad * 8);
                bf16x8 b   = ld_bf16x8_a8(vh + brow + ks * 32 + quad * 8);
                bf16x8 bl8 = ld_bf16x8_a8(vl + brow + ks * 32 + quad * 8);
                acc = __builtin_amdgcn_mfma_f32_16x16x32_bf16(a, b, acc, 0, 0, 0);
                acc = __builtin_amdgcn_mfma_f32_16x16x32_bf16(al8, b, acc, 0, 0, 0);
                acc = __builtin_amdgcn_mfma_f32_16x16x32_bf16(a, bl8, acc, 0, 0, 0);
            }
            int dd = nd * 16 + l15, sbase = mq * 16 + quad * 4;
            float2 vdd = *(const float2*)(smem + V64_OFF + dd * 8);
            float o[4];
            #pragma unroll
            for (int reg = 0; reg < 4; ++reg) {
                int qs = sbase + reg;
                float2 p2 = *(const float2*)(smem + P64_OFF + qs * 8);
                float tv = acc[reg] + p2.x * vdd.x + p2.y * vdd.y;
                o[reg] = (qs < 66) ? tv * inv[qs] : 0.f;
            }
            if (sbase < 64) {
                uint2 pk;
                pk.x = cvtpk(o[0], o[1]);
                pk.y = cvtpk(o[2], o[3]);
                *(uint2*)(smem + AOT_OFF + dd * 136 + 2 * sbase) = pk;
            } else if (quad == 0) {    // sbase==64: qs 64,65 exact f32
                *(float2*)(smem + AO64_OFF + dd * 8) = (float2){o[0], o[1]};
            }
        }
    }
    __syncthreads();

    // ------- Phase 6: out = Wc @ ao + bc; Wc frags from global + f32 tail s=64,65 ----
    {
        const short* aoT = (const short*)(smem + AOT_OFF);
        int mj = wid >> 1, nd = wid & 1;
        f32x4 acc = (f32x4){0.f, 0.f, 0.f, 0.f};
        #pragma unroll
        for (int ks = 0; ks < 2; ++ks) {
            bf16x8 a, al8;
            if constexpr (MODE >= 1) {
                const unsigned char* wt = ws + WSWC_OFF + ((mj * 2 + ks) << 10) + (lane << 4);
                a   = *(const bf16x8*)(wt);
                al8 = *(const bf16x8*)(wt + 4096);
            } else {
                float4 w0 = {0.f,0.f,0.f,0.f}, w1 = w0;
                int jr = mj * 16 + l15;
                if (jr < 22) {
                    const float* p = Wc + jr * 66 + ks * 32 + quad * 8;
                    w0 = *(const float4*)p;
                    w1 = *(const float4*)(p + 4);
                }
                uint4 uh, ul;
                split2(w0.x, w0.y, uh.x, ul.x);
                split2(w0.z, w0.w, uh.y, ul.y);
                split2(w1.x, w1.y, uh.z, ul.z);
                split2(w1.z, w1.w, uh.w, ul.w);
                a   = *(bf16x8*)&uh;
                al8 = *(bf16x8*)&ul;
            }
            bf16x8 b = ld_bf16x8_a8(aoT + (nd * 16 + l15) * PV_ROW + ks * 32 + quad * 8);
            acc = __builtin_amdgcn_mfma_f32_16x16x32_bf16(a, b, acc, 0, 0, 0);
            acc = __builtin_amdgcn_mfma_f32_16x16x32_bf16(al8, b, acc, 0, 0, 0);
        }
        int dd = nd * 16 + l15;
        float2 ao2 = *(const float2*)(smem + AO64_OFF + dd * 8);
        #pragma unroll
        for (int reg = 0; reg < 4; ++reg) {
            int j = mj * 16 + quad * 4 + reg;
            if (j < 22) {
                float w64a = Wc[j * 66 + 64], w64b = Wc[j * 66 + 65];
                float r = acc[reg] + w64a * ao2.x + w64b * ao2.y + bc[j];
                size_t o = (size_t)(bt * J + j) * (H * D) + h * 32 + dd;
                out[o] = r;
            }
        }
    }
}

extern "C" void kernel_launch(void* const* d_in, const int* in_sizes, int n_in,
                              void* d_out, int out_size, void* d_ws, size_t ws_size,
                              hipStream_t stream) {
    const float* x  = (const float*)d_in[0];
    const float* Wq = (const float*)d_in[1];
    const float* bq = (const float*)d_in[2];
    const float* Wk = (const float*)d_in[3];
    const float* bk = (const float*)d_in[4];
    const float* Wv = (const float*)d_in[5];
    const float* bv = (const float*)d_in[6];
    const float* Wc = (const float*)d_in[7];
    const float* bc = (const float*)d_in[8];
    float* out = (float*)d_out;

    const int B = 512;
    dim3 grid(B * T * H), block(256);
    if (d_ws != nullptr && ws_size >= WS_FULL) {
        hipLaunchKernelGGL(presplit_all, dim3(199 + 12288), dim3(256), 0, stream,
                           Wq, Wk, Wv, Wc, x, (unsigned char*)d_ws);
        hipLaunchKernelGGL((mha_fused_kernel<2>), grid, block, 0, stream,
                           x, Wq, bq, Wk, bk, Wv, bv, Wc, bc,
                           (const unsigned char*)d_ws, out);
    } else if (d_ws != nullptr && ws_size >= WS_W) {
        hipLaunchKernelGGL(presplit_all, dim3(199), dim3(256), 0, stream,
                           Wq, Wk, Wv, Wc, x, (unsigned char*)d_ws);
        hipLaunchKernelGGL((mha_fused_kernel<1>), grid, block, 0, stream,
                           x, Wq, bq, Wk, bk, Wv, bv, Wc, bc,
                           (const unsigned char*)d_ws, out);
    } else {
        hipLaunchKernelGGL((mha_fused_kernel<0>), grid, block, 0, stream,
                           x, Wq, bq, Wk, bk, Wv, bv, Wc, bc,
                           (const unsigned char*)nullptr, out);
    }
}